// Round 1
// baseline (9570.622 us; speedup 1.0000x reference)
//
#include <hip/hip_runtime.h>
#include <math.h>

#define NM 16
#define TT 8192
#define HH 128
#define G3 384

// ---------------- K0: per-mic standardize (mean, std ddof=1) ----------------
__global__ void k_norm(const float* __restrict__ samples, float* __restrict__ s_out) {
    int mic = blockIdx.x;
    const float* x = samples + (long)mic * TT;
    __shared__ float red[256];
    int tid = threadIdx.x;
    float acc = 0.f;
    for (int i = tid; i < TT; i += 256) acc += x[i];
    red[tid] = acc; __syncthreads();
    for (int off = 128; off > 0; off >>= 1) { if (tid < off) red[tid] += red[tid + off]; __syncthreads(); }
    float mu = red[0] / (float)TT;
    __syncthreads();
    float acc2 = 0.f;
    for (int i = tid; i < TT; i += 256) { float d = x[i] - mu; acc2 += d * d; }
    red[tid] = acc2; __syncthreads();
    for (int off = 128; off > 0; off >>= 1) { if (tid < off) red[tid] += red[tid + off]; __syncthreads(); }
    float inv = rsqrtf(red[0] / (float)(TT - 1));
    for (int i = tid; i < TT; i += 256) s_out[(long)mic * TT + i] = (x[i] - mu) * inv;
}

// ---------------- K1: gi[t][j] = sum_m s[m][t]*w_ih[j][m] + b_ih[j] ----------------
__global__ void k_gi(const float* __restrict__ s, const float* __restrict__ w_ih,
                     const float* __restrict__ b_ih, float* __restrict__ gi) {
    int t = blockIdx.x;
    __shared__ float sv[NM];
    int tid = threadIdx.x;            // 0..383
    if (tid < NM) sv[tid] = s[(long)tid * TT + t];
    __syncthreads();
    float acc = b_ih[tid];
    const float* wr = w_ih + tid * NM;
#pragma unroll
    for (int m = 0; m < NM; ++m) acc += wr[m] * sv[m];
    gi[(long)t * G3 + tid] = acc;
}

// ---------------- K2: sequential GRU scan, single workgroup ----------------
__launch_bounds__(G3, 1)
__global__ void k_gru(const float* __restrict__ gi, const float* __restrict__ w_hh,
                      const float* __restrict__ b_hh, float* __restrict__ h_out) {
    __shared__ __align__(16) float h[HH];
    __shared__ float gh[G3];
    int tid = threadIdx.x;            // 0..383
    // each thread owns one row of w_hh (128 f32 in VGPRs)
    float4 w[32];
    const float4* wrow = (const float4*)(w_hh + (long)tid * HH);
#pragma unroll
    for (int k = 0; k < 32; ++k) w[k] = wrow[k];
    float bh = b_hh[tid];
    float h_reg = 0.f;
    if (tid < HH) h[tid] = 0.f;
    // prefetch gi[0]
    float gA = 0.f, gB = 0.f, gC = 0.f;
    if (tid < HH) { gA = gi[tid]; gB = gi[HH + tid]; gC = gi[2 * HH + tid]; }
    __syncthreads();
    const float4* h4 = (const float4*)h;
    for (int t = 0; t < TT; ++t) {
        // prefetch next step's gi slice (hidden under the matvec)
        float nA = 0.f, nB = 0.f, nC = 0.f;
        if (tid < HH && t + 1 < TT) {
            const float* g = gi + (long)(t + 1) * G3;
            nA = g[tid]; nB = g[HH + tid]; nC = g[2 * HH + tid];
        }
        // gh = w_hh @ h  (row per thread, h broadcast from LDS)
        float a0 = 0.f, a1 = 0.f, a2 = 0.f, a3 = 0.f;
#pragma unroll
        for (int k = 0; k < 32; k += 4) {
            float4 x0 = h4[k], x1 = h4[k + 1], x2 = h4[k + 2], x3 = h4[k + 3];
            a0 += w[k].x * x0.x + w[k].y * x0.y + w[k].z * x0.z + w[k].w * x0.w;
            a1 += w[k + 1].x * x1.x + w[k + 1].y * x1.y + w[k + 1].z * x1.z + w[k + 1].w * x1.w;
            a2 += w[k + 2].x * x2.x + w[k + 2].y * x2.y + w[k + 2].z * x2.z + w[k + 2].w * x2.w;
            a3 += w[k + 3].x * x3.x + w[k + 3].y * x3.y + w[k + 3].z * x3.z + w[k + 3].w * x3.w;
        }
        gh[tid] = (a0 + a1) + (a2 + a3) + bh;
        __syncthreads();
        if (tid < HH) {
            float xr = gA + gh[tid];
            float xz = gB + gh[HH + tid];
            float r = 1.f / (1.f + __expf(-xr));
            float z = 1.f / (1.f + __expf(-xz));
            float xn = gC + r * gh[2 * HH + tid];
            xn = fminf(fmaxf(xn, -20.f), 20.f);
            float e2 = __expf(2.f * xn);
            float n = (e2 - 1.f) / (e2 + 1.f);
            h_reg = (1.f - z) * n + z * h_reg;
            h[tid] = h_reg;
        }
        gA = nA; gB = nB; gC = nC;
        __syncthreads();
    }
    if (tid < HH) h_out[tid] = h_reg;
}

// ---------------- K3: v = w_post@h + b_post; c from rank-1 eigh model ----------------
__global__ void k_eig(const float* __restrict__ h_last, const float* __restrict__ w_post,
                      const float* __restrict__ b_post, const int* __restrict__ ns_p,
                      float* __restrict__ c_out) {
    __shared__ float v[NM];
    int tid = threadIdx.x;
    if (tid < NM) {
        float acc = b_post[tid];
        const float* wr = w_post + tid * HH;
        for (int k = 0; k < HH; ++k) acc += wr[k] * h_last[k];
        v[tid] = acc;
    }
    __syncthreads();
    if (tid == 0) {
        float S1 = 0.f, vv = 0.f;
        for (int i = 0; i < NM; ++i) { S1 += v[i]; vv += v[i] * v[i]; }
        // ||p||^2 = ||P_null 1||^2 ; null dim = NM-1 (rank-1 cov)
        float pp = (float)NM - S1 * S1 / vv;
        int nn = NM - ns_p[0];                      // 13 noise dirs kept of 15
        // chaos-expectation model of LAPACK's degenerate-basis choice:
        float kept = pp * ((float)nn / (float)(NM - 1));
        c_out[0] = 1.f / sqrtf(kept);               // spectrum value (constant over thetas)
    }
}

// ---------------- K4: h1 = gelu(c * rowsum(w1) + b1) ----------------
__global__ void k_h1(const float* __restrict__ w1, const float* __restrict__ b1,
                     const float* __restrict__ c_p, float* __restrict__ h1) {
    int row = blockIdx.x;            // 0..255
    int tid = threadIdx.x;           // 0..255
    const float4* wr = (const float4*)(w1 + (long)row * 65536);
    float acc = 0.f;
    for (int i = tid; i < 16384; i += 256) { float4 x = wr[i]; acc += (x.x + x.y) + (x.z + x.w); }
    __shared__ float red[256];
    red[tid] = acc; __syncthreads();
    for (int off = 128; off > 0; off >>= 1) { if (tid < off) red[tid] += red[tid + off]; __syncthreads(); }
    if (tid == 0) {
        float x = c_p[0] * red[0] + b1[row];
        h1[row] = 0.5f * x * (1.f + erff(x * 0.70710678118654752f));
    }
}

// ---------------- K5: h2 = gelu(w2@h1+b2); out = sigmoid(w3@h2+b3)*2pi ----------------
__global__ void k_out(const float* __restrict__ h1, const float* __restrict__ w2,
                      const float* __restrict__ b2, const float* __restrict__ w3,
                      const float* __restrict__ b3, float* __restrict__ out) {
    __shared__ float h2[256];
    int tid = threadIdx.x;           // 0..255
    float acc = b2[tid];
    const float* wr = w2 + tid * 256;
    for (int k = 0; k < 256; ++k) acc += wr[k] * h1[k];
    h2[tid] = 0.5f * acc * (1.f + erff(acc * 0.70710678118654752f));
    __syncthreads();
    if (tid < NM) {
        float a = b3[tid];
        const float* wr3 = w3 + tid * 256;
        for (int k = 0; k < 256; ++k) a += wr3[k] * h2[k];
        out[tid] = (1.f / (1.f + expf(-a))) * 6.283185307179586f;
    }
}

extern "C" void kernel_launch(void* const* d_in, const int* in_sizes, int n_in,
                              void* d_out, int out_size, void* d_ws, size_t ws_size,
                              hipStream_t stream) {
    const float* samples = (const float*)d_in[0];
    const int*   n_src   = (const int*)d_in[1];
    // d_in[2] = mic_locations: dead (mf==0 -> atheta==1)
    const float* w_ih   = (const float*)d_in[3];
    const float* w_hh   = (const float*)d_in[4];
    const float* b_ih   = (const float*)d_in[5];
    const float* b_hh   = (const float*)d_in[6];
    const float* w_post = (const float*)d_in[7];
    const float* b_post = (const float*)d_in[8];
    const float* w1     = (const float*)d_in[9];
    const float* b1     = (const float*)d_in[10];
    const float* w2     = (const float*)d_in[11];
    const float* b2     = (const float*)d_in[12];
    const float* w3     = (const float*)d_in[13];
    const float* b3     = (const float*)d_in[14];
    float* out = (float*)d_out;

    float* ws     = (float*)d_ws;
    float* s      = ws;                       // 16*8192
    float* gi     = s + NM * TT;              // 8192*384
    float* h_last = gi + (long)TT * G3;       // 128
    float* c_p    = h_last + HH;              // 1
    float* h1     = c_p + 1;                  // 256

    hipLaunchKernelGGL(k_norm, dim3(NM),   dim3(256), 0, stream, samples, s);
    hipLaunchKernelGGL(k_gi,   dim3(TT),   dim3(G3),  0, stream, s, w_ih, b_ih, gi);
    hipLaunchKernelGGL(k_gru,  dim3(1),    dim3(G3),  0, stream, gi, w_hh, b_hh, h_last);
    hipLaunchKernelGGL(k_eig,  dim3(1),    dim3(64),  0, stream, h_last, w_post, b_post, n_src, c_p);
    hipLaunchKernelGGL(k_h1,   dim3(256),  dim3(256), 0, stream, w1, b1, c_p, h1);
    hipLaunchKernelGGL(k_out,  dim3(1),    dim3(256), 0, stream, h1, w2, b2, w3, b3, out);
}

// Round 2
// 5292.646 us; speedup vs baseline: 1.8083x; 1.8083x over previous
//
#include <hip/hip_runtime.h>
#include <math.h>

#define NM 16
#define TT 8192
#define HH 128
#define G3 384

typedef _Float16 half_t;
typedef _Float16 h2_t __attribute__((ext_vector_type(2)));
typedef _Float16 h8_t __attribute__((ext_vector_type(8)));

#if defined(__has_builtin)
#if __has_builtin(__builtin_amdgcn_fdot2)
#define HAS_FDOT2 1
#endif
#endif

__device__ __forceinline__ float dot2acc(h2_t a, h2_t b, float c) {
#ifdef HAS_FDOT2
    return __builtin_amdgcn_fdot2(a, b, c, false);
#else
    return fmaf((float)a[0], (float)b[0], fmaf((float)a[1], (float)b[1], c));
#endif
}

// ---------------- K0: per-mic standardize (mean, std ddof=1) ----------------
__global__ void k_norm(const float* __restrict__ samples, float* __restrict__ s_out) {
    int mic = blockIdx.x;
    const float* x = samples + (long)mic * TT;
    __shared__ float red[256];
    int tid = threadIdx.x;
    float acc = 0.f;
    for (int i = tid; i < TT; i += 256) acc += x[i];
    red[tid] = acc; __syncthreads();
    for (int off = 128; off > 0; off >>= 1) { if (tid < off) red[tid] += red[tid + off]; __syncthreads(); }
    float mu = red[0] / (float)TT;
    __syncthreads();
    float acc2 = 0.f;
    for (int i = tid; i < TT; i += 256) { float d = x[i] - mu; acc2 += d * d; }
    red[tid] = acc2; __syncthreads();
    for (int off = 128; off > 0; off >>= 1) { if (tid < off) red[tid] += red[tid + off]; __syncthreads(); }
    float inv = rsqrtf(red[0] / (float)(TT - 1));
    for (int i = tid; i < TT; i += 256) s_out[(long)mic * TT + i] = (x[i] - mu) * inv;
}

// ---------------- K1: gi[t][j] = sum_m s[m][t]*w_ih[j][m] + b_ih[j] ----------------
__global__ void k_gi(const float* __restrict__ s, const float* __restrict__ w_ih,
                     const float* __restrict__ b_ih, float* __restrict__ gi) {
    int t = blockIdx.x;
    __shared__ float sv[NM];
    int tid = threadIdx.x;            // 0..383
    if (tid < NM) sv[tid] = s[(long)tid * TT + t];
    __syncthreads();
    float acc = b_ih[tid];
    const float* wr = w_ih + tid * NM;
#pragma unroll
    for (int m = 0; m < NM; ++m) acc += wr[m] * sv[m];
    gi[(long)t * G3 + tid] = acc;
}

// ---------------- K2: sequential GRU scan, 128 threads, all 3 gates in-thread ----------------
// Each thread owns rows {tid, 128+tid, 256+tid} of w_hh as packed f16 in VGPRs.
// h is double-buffered packed-f16 in LDS -> ONE barrier per step, no gh exchange.
__launch_bounds__(HH, 1)
__global__ void k_gru(const float* __restrict__ gi, const float* __restrict__ w_hh,
                      const float* __restrict__ b_hh, float* __restrict__ h_out) {
    __shared__ __align__(16) h2_t hb[2][HH / 2];
    int tid = threadIdx.x;            // 0..127

    // convert this thread's three w_hh rows to packed f16
    h2_t wr[64], wz[64], wn[64];
    {
        const float4* r4 = (const float4*)(w_hh + (long)tid * HH);
        const float4* z4 = (const float4*)(w_hh + (long)(HH + tid) * HH);
        const float4* n4 = (const float4*)(w_hh + (long)(2 * HH + tid) * HH);
#pragma unroll
        for (int k = 0; k < 32; ++k) {
            float4 a = r4[k]; wr[2 * k] = h2_t{(half_t)a.x, (half_t)a.y}; wr[2 * k + 1] = h2_t{(half_t)a.z, (half_t)a.w};
            float4 b = z4[k]; wz[2 * k] = h2_t{(half_t)b.x, (half_t)b.y}; wz[2 * k + 1] = h2_t{(half_t)b.z, (half_t)b.w};
            float4 c = n4[k]; wn[2 * k] = h2_t{(half_t)c.x, (half_t)c.y}; wn[2 * k + 1] = h2_t{(half_t)c.z, (half_t)c.w};
        }
    }
    float bhr = b_hh[tid], bhz = b_hh[HH + tid], bhn = b_hh[2 * HH + tid];

    if (tid < HH / 2) hb[0][tid] = h2_t{(half_t)0.f, (half_t)0.f};
    float h_reg = 0.f;
    float gA = gi[tid], gB = gi[HH + tid], gC = gi[2 * HH + tid];
    __syncthreads();

    int p = 0;
    for (int t = 0; t < TT; ++t) {
        // prefetch next step's gi slice (hidden under the matvec)
        float nA = 0.f, nB = 0.f, nC = 0.f;
        if (t + 1 < TT) {
            const float* g = gi + (long)(t + 1) * G3;
            nA = g[tid]; nB = g[HH + tid]; nC = g[2 * HH + tid];
        }
        // three dot products vs broadcast h (packed f16, ds_read_b128 chunks)
        const h8_t* hp = (const h8_t*)hb[p];
        float ar0 = 0.f, ar1 = 0.f, az0 = 0.f, az1 = 0.f, an0 = 0.f, an1 = 0.f;
#pragma unroll
        for (int c = 0; c < 16; ++c) {
            h8_t hc = hp[c];
            h2_t p0 = h2_t{hc[0], hc[1]};
            h2_t p1 = h2_t{hc[2], hc[3]};
            h2_t p2 = h2_t{hc[4], hc[5]};
            h2_t p3 = h2_t{hc[6], hc[7]};
            int k = c * 4;
            ar0 = dot2acc(wr[k], p0, ar0); ar1 = dot2acc(wr[k + 1], p1, ar1);
            ar0 = dot2acc(wr[k + 2], p2, ar0); ar1 = dot2acc(wr[k + 3], p3, ar1);
            az0 = dot2acc(wz[k], p0, az0); az1 = dot2acc(wz[k + 1], p1, az1);
            az0 = dot2acc(wz[k + 2], p2, az0); az1 = dot2acc(wz[k + 3], p3, az1);
            an0 = dot2acc(wn[k], p0, an0); an1 = dot2acc(wn[k + 1], p1, an1);
            an0 = dot2acc(wn[k + 2], p2, an0); an1 = dot2acc(wn[k + 3], p3, an1);
        }
        float xr = gA + (ar0 + ar1) + bhr;
        float xz = gB + (az0 + az1) + bhz;
        float r = 1.f / (1.f + __expf(-xr));
        float z = 1.f / (1.f + __expf(-xz));
        float xn = gC + r * ((an0 + an1) + bhn);
        xn = fminf(fmaxf(xn, -20.f), 20.f);
        float e2 = __expf(2.f * xn);
        float n = (e2 - 1.f) / (e2 + 1.f);
        h_reg = (1.f - z) * n + z * h_reg;
        ((half_t*)hb[1 - p])[tid] = (half_t)h_reg;
        gA = nA; gB = nB; gC = nC;
        __syncthreads();
        p ^= 1;
    }
    h_out[tid] = h_reg;
}

// ---------------- K3: v = w_post@h + b_post; c from rank-1 eigh model ----------------
__global__ void k_eig(const float* __restrict__ h_last, const float* __restrict__ w_post,
                      const float* __restrict__ b_post, const int* __restrict__ ns_p,
                      float* __restrict__ c_out) {
    __shared__ float v[NM];
    int tid = threadIdx.x;
    if (tid < NM) {
        float acc = b_post[tid];
        const float* wr = w_post + tid * HH;
        for (int k = 0; k < HH; ++k) acc += wr[k] * h_last[k];
        v[tid] = acc;
    }
    __syncthreads();
    if (tid == 0) {
        float S1 = 0.f, vv = 0.f;
        for (int i = 0; i < NM; ++i) { S1 += v[i]; vv += v[i] * v[i]; }
        // ||p||^2 = ||P_null 1||^2 ; null dim = NM-1 (rank-1 cov)
        float pp = (float)NM - S1 * S1 / vv;
        int nn = NM - ns_p[0];                      // 13 noise dirs kept of 15
        // chaos-expectation model of LAPACK's degenerate-basis choice:
        float kept = pp * ((float)nn / (float)(NM - 1));
        c_out[0] = 1.f / sqrtf(kept);               // spectrum value (constant over thetas)
    }
}

// ---------------- K4: h1 = gelu(c * rowsum(w1) + b1) ----------------
__global__ void k_h1(const float* __restrict__ w1, const float* __restrict__ b1,
                     const float* __restrict__ c_p, float* __restrict__ h1) {
    int row = blockIdx.x;            // 0..255
    int tid = threadIdx.x;           // 0..255
    const float4* wr = (const float4*)(w1 + (long)row * 65536);
    float acc = 0.f;
    for (int i = tid; i < 16384; i += 256) { float4 x = wr[i]; acc += (x.x + x.y) + (x.z + x.w); }
    __shared__ float red[256];
    red[tid] = acc; __syncthreads();
    for (int off = 128; off > 0; off >>= 1) { if (tid < off) red[tid] += red[tid + off]; __syncthreads(); }
    if (tid == 0) {
        float x = c_p[0] * red[0] + b1[row];
        h1[row] = 0.5f * x * (1.f + erff(x * 0.70710678118654752f));
    }
}

// ---------------- K5: h2 = gelu(w2@h1+b2); out = sigmoid(w3@h2+b3)*2pi ----------------
__global__ void k_out(const float* __restrict__ h1, const float* __restrict__ w2,
                      const float* __restrict__ b2, const float* __restrict__ w3,
                      const float* __restrict__ b3, float* __restrict__ out) {
    __shared__ float h2[256];
    int tid = threadIdx.x;           // 0..255
    float acc = b2[tid];
    const float* wr = w2 + tid * 256;
    for (int k = 0; k < 256; ++k) acc += wr[k] * h1[k];
    h2[tid] = 0.5f * acc * (1.f + erff(acc * 0.70710678118654752f));
    __syncthreads();
    if (tid < NM) {
        float a = b3[tid];
        const float* wr3 = w3 + tid * 256;
        for (int k = 0; k < 256; ++k) a += wr3[k] * h2[k];
        out[tid] = (1.f / (1.f + expf(-a))) * 6.283185307179586f;
    }
}

extern "C" void kernel_launch(void* const* d_in, const int* in_sizes, int n_in,
                              void* d_out, int out_size, void* d_ws, size_t ws_size,
                              hipStream_t stream) {
    const float* samples = (const float*)d_in[0];
    const int*   n_src   = (const int*)d_in[1];
    // d_in[2] = mic_locations: dead (mf==0 -> atheta==1)
    const float* w_ih   = (const float*)d_in[3];
    const float* w_hh   = (const float*)d_in[4];
    const float* b_ih   = (const float*)d_in[5];
    const float* b_hh   = (const float*)d_in[6];
    const float* w_post = (const float*)d_in[7];
    const float* b_post = (const float*)d_in[8];
    const float* w1     = (const float*)d_in[9];
    const float* b1     = (const float*)d_in[10];
    const float* w2     = (const float*)d_in[11];
    const float* b2     = (const float*)d_in[12];
    const float* w3     = (const float*)d_in[13];
    const float* b3     = (const float*)d_in[14];
    float* out = (float*)d_out;

    float* ws     = (float*)d_ws;
    float* s      = ws;                       // 16*8192
    float* gi     = s + NM * TT;              // 8192*384
    float* h_last = gi + (long)TT * G3;       // 128
    float* c_p    = h_last + HH;              // 1
    float* h1     = c_p + 1;                  // 256

    hipLaunchKernelGGL(k_norm, dim3(NM),   dim3(256), 0, stream, samples, s);
    hipLaunchKernelGGL(k_gi,   dim3(TT),   dim3(G3),  0, stream, s, w_ih, b_ih, gi);
    hipLaunchKernelGGL(k_gru,  dim3(1),    dim3(HH),  0, stream, gi, w_hh, b_hh, h_last);
    hipLaunchKernelGGL(k_eig,  dim3(1),    dim3(64),  0, stream, h_last, w_post, b_post, n_src, c_p);
    hipLaunchKernelGGL(k_h1,   dim3(256),  dim3(256), 0, stream, w1, b1, c_p, h1);
    hipLaunchKernelGGL(k_out,  dim3(1),    dim3(256), 0, stream, h1, w2, b2, w3, b3, out);
}

// Round 3
// 4166.043 us; speedup vs baseline: 2.2973x; 1.2704x over previous
//
#include <hip/hip_runtime.h>
#include <math.h>

#define NM 16
#define TT 8192
#define HH 128
#define G3 384
#define BT 256

typedef _Float16 half_t;
typedef _Float16 h2_t __attribute__((ext_vector_type(2)));

#if defined(__has_builtin)
#if __has_builtin(__builtin_amdgcn_fdot2)
#define HAS_FDOT2 1
#endif
#endif

__device__ __forceinline__ float dot2acc(h2_t a, h2_t b, float c) {
#ifdef HAS_FDOT2
    return __builtin_amdgcn_fdot2(a, b, c, false);
#else
    return fmaf((float)a[0], (float)b[0], fmaf((float)a[1], (float)b[1], c));
#endif
}

__device__ __forceinline__ h2_t u2h(unsigned int u) {
    return __builtin_bit_cast(h2_t, u);
}

// ---------------- K0: per-mic standardize (mean, std ddof=1) ----------------
__global__ void k_norm(const float* __restrict__ samples, float* __restrict__ s_out) {
    int mic = blockIdx.x;
    const float* x = samples + (long)mic * TT;
    __shared__ float red[256];
    int tid = threadIdx.x;
    float acc = 0.f;
    for (int i = tid; i < TT; i += 256) acc += x[i];
    red[tid] = acc; __syncthreads();
    for (int off = 128; off > 0; off >>= 1) { if (tid < off) red[tid] += red[tid + off]; __syncthreads(); }
    float mu = red[0] / (float)TT;
    __syncthreads();
    float acc2 = 0.f;
    for (int i = tid; i < TT; i += 256) { float d = x[i] - mu; acc2 += d * d; }
    red[tid] = acc2; __syncthreads();
    for (int off = 128; off > 0; off >>= 1) { if (tid < off) red[tid] += red[tid + off]; __syncthreads(); }
    float inv = rsqrtf(red[0] / (float)(TT - 1));
    for (int i = tid; i < TT; i += 256) s_out[(long)mic * TT + i] = (x[i] - mu) * inv;
}

// ---------------- K1: gi[t][j] = sum_m s[m][t]*w_ih[j][m] + b_ih[j] ----------------
__global__ void k_gi(const float* __restrict__ s, const float* __restrict__ w_ih,
                     const float* __restrict__ b_ih, float* __restrict__ gi) {
    int t = blockIdx.x;
    __shared__ float sv[NM];
    int tid = threadIdx.x;            // 0..383
    if (tid < NM) sv[tid] = s[(long)tid * TT + t];
    __syncthreads();
    float acc = b_ih[tid];
    const float* wr = w_ih + tid * NM;
#pragma unroll
    for (int m = 0; m < NM; ++m) acc += wr[m] * sv[m];
    gi[(long)t * G3 + tid] = acc;
}

// ---------------- K2: sequential GRU scan ----------------
// 256 threads = 4 waves (1 per SIMD). Thread t: h-index j=t>>1, k-half=t&1.
// Owns 3 gate rows x 64 cols as packed f16 (96 VGPRs). Pair-reduce via
// shfl_xor(1); pointwise fully in-lane; ONE barrier/step (double-buffered h).
__launch_bounds__(BT, 1)
__global__ void k_gru(const float* __restrict__ gi, const float* __restrict__ w_hh,
                      const float* __restrict__ b_hh, float* __restrict__ h_out) {
    __shared__ __align__(16) half_t hb[2][HH];
    int tid = threadIdx.x;            // 0..255
    int j = tid >> 1;                 // 0..127
    int half = tid & 1;               // k-half
    int k0 = half * 64;

    h2_t wr[32], wz[32], wn[32];
    {
        const float2* r2 = (const float2*)(w_hh + (long)j * HH + k0);
        const float2* z2 = (const float2*)(w_hh + (long)(HH + j) * HH + k0);
        const float2* n2 = (const float2*)(w_hh + (long)(2 * HH + j) * HH + k0);
#pragma unroll
        for (int k = 0; k < 32; ++k) {
            float2 a = r2[k]; wr[k] = h2_t{(half_t)a.x, (half_t)a.y};
            float2 b = z2[k]; wz[k] = h2_t{(half_t)b.x, (half_t)b.y};
            float2 c = n2[k]; wn[k] = h2_t{(half_t)c.x, (half_t)c.y};
        }
    }
    float bhr = b_hh[j], bhz = b_hh[HH + j], bhn = b_hh[2 * HH + j];

    if (tid < HH) hb[0][tid] = (half_t)0.f;
    float h_reg = 0.f;
    float gA = gi[j], gB = gi[HH + j], gC = gi[2 * HH + j];
    __syncthreads();

    int p = 0;
    for (int t = 0; t < TT; ++t) {
        // uniform branchless prefetch of next step's gi (hidden under dots)
        const float* gn = gi + (long)(t + 1 < TT ? t + 1 : t) * G3;
        float nA = gn[j], nB = gn[HH + j], nC = gn[2 * HH + j];

        // h half-slice as 8x ds_read_b128, dwords bit-cast to h2 (no pack VALU)
        const uint4* hp = (const uint4*)(&hb[p][k0]);
        float ar0 = 0.f, ar1 = 0.f, az0 = 0.f, az1 = 0.f, an0 = 0.f, an1 = 0.f;
#pragma unroll
        for (int c = 0; c < 8; ++c) {
            uint4 hv = hp[c];
            h2_t p0 = u2h(hv.x), p1 = u2h(hv.y), p2 = u2h(hv.z), p3 = u2h(hv.w);
            int k = c * 4;
            ar0 = dot2acc(wr[k], p0, ar0); ar1 = dot2acc(wr[k + 1], p1, ar1);
            ar0 = dot2acc(wr[k + 2], p2, ar0); ar1 = dot2acc(wr[k + 3], p3, ar1);
            az0 = dot2acc(wz[k], p0, az0); az1 = dot2acc(wz[k + 1], p1, az1);
            az0 = dot2acc(wz[k + 2], p2, az0); az1 = dot2acc(wz[k + 3], p3, az1);
            an0 = dot2acc(wn[k], p0, an0); an1 = dot2acc(wn[k + 1], p1, an1);
            an0 = dot2acc(wn[k + 2], p2, an0); an1 = dot2acc(wn[k + 3], p3, an1);
        }
        float ar = ar0 + ar1, az = az0 + az1, an = an0 + an1;
        // pair-reduce across k-halves (partner = lane^1, same wave)
        ar += __shfl_xor(ar, 1);
        az += __shfl_xor(az, 1);
        an += __shfl_xor(an, 1);

        // pointwise, fully in-lane (both pair lanes compute identically)
        float xr = gA + ar + bhr;
        float xz = gB + az + bhz;
        float r = 1.f / (1.f + __expf(-xr));
        float z = 1.f / (1.f + __expf(-xz));
        float xn = gC + r * (an + bhn);
        xn = fminf(fmaxf(xn, -20.f), 20.f);
        float e2 = __expf(2.f * xn);
        float n = (e2 - 1.f) / (e2 + 1.f);
        h_reg = (1.f - z) * n + z * h_reg;
        if (!half) hb[1 - p][j] = (half_t)h_reg;

        gA = nA; gB = nB; gC = nC;
        __syncthreads();
        p ^= 1;
    }
    if (!half) h_out[j] = h_reg;
}

// ---------------- K3: v = w_post@h + b_post; c from rank-1 eigh model ----------------
__global__ void k_eig(const float* __restrict__ h_last, const float* __restrict__ w_post,
                      const float* __restrict__ b_post, const int* __restrict__ ns_p,
                      float* __restrict__ c_out) {
    __shared__ float v[NM];
    int tid = threadIdx.x;
    if (tid < NM) {
        float acc = b_post[tid];
        const float* wr = w_post + tid * HH;
        for (int k = 0; k < HH; ++k) acc += wr[k] * h_last[k];
        v[tid] = acc;
    }
    __syncthreads();
    if (tid == 0) {
        float S1 = 0.f, vv = 0.f;
        for (int i = 0; i < NM; ++i) { S1 += v[i]; vv += v[i] * v[i]; }
        // ||p||^2 = ||P_null 1||^2 ; null dim = NM-1 (rank-1 cov)
        float pp = (float)NM - S1 * S1 / vv;
        int nn = NM - ns_p[0];                      // 13 noise dirs kept of 15
        // chaos-expectation model of LAPACK's degenerate-basis choice:
        float kept = pp * ((float)nn / (float)(NM - 1));
        c_out[0] = 1.f / sqrtf(kept);               // spectrum value (constant over thetas)
    }
}

// ---------------- K4: h1 = gelu(c * rowsum(w1) + b1) ----------------
__global__ void k_h1(const float* __restrict__ w1, const float* __restrict__ b1,
                     const float* __restrict__ c_p, float* __restrict__ h1) {
    int row = blockIdx.x;            // 0..255
    int tid = threadIdx.x;           // 0..255
    const float4* wr = (const float4*)(w1 + (long)row * 65536);
    float acc = 0.f;
    for (int i = tid; i < 16384; i += 256) { float4 x = wr[i]; acc += (x.x + x.y) + (x.z + x.w); }
    __shared__ float red[256];
    red[tid] = acc; __syncthreads();
    for (int off = 128; off > 0; off >>= 1) { if (tid < off) red[tid] += red[tid + off]; __syncthreads(); }
    if (tid == 0) {
        float x = c_p[0] * red[0] + b1[row];
        h1[row] = 0.5f * x * (1.f + erff(x * 0.70710678118654752f));
    }
}

// ---------------- K5: h2 = gelu(w2@h1+b2); out = sigmoid(w3@h2+b3)*2pi ----------------
__global__ void k_out(const float* __restrict__ h1, const float* __restrict__ w2,
                      const float* __restrict__ b2, const float* __restrict__ w3,
                      const float* __restrict__ b3, float* __restrict__ out) {
    __shared__ float h2[256];
    int tid = threadIdx.x;           // 0..255
    float acc = b2[tid];
    const float* wr = w2 + tid * 256;
    for (int k = 0; k < 256; ++k) acc += wr[k] * h1[k];
    h2[tid] = 0.5f * acc * (1.f + erff(acc * 0.70710678118654752f));
    __syncthreads();
    if (tid < NM) {
        float a = b3[tid];
        const float* wr3 = w3 + tid * 256;
        for (int k = 0; k < 256; ++k) a += wr3[k] * h2[k];
        out[tid] = (1.f / (1.f + expf(-a))) * 6.283185307179586f;
    }
}

extern "C" void kernel_launch(void* const* d_in, const int* in_sizes, int n_in,
                              void* d_out, int out_size, void* d_ws, size_t ws_size,
                              hipStream_t stream) {
    const float* samples = (const float*)d_in[0];
    const int*   n_src   = (const int*)d_in[1];
    // d_in[2] = mic_locations: dead (mf==0 -> atheta==1)
    const float* w_ih   = (const float*)d_in[3];
    const float* w_hh   = (const float*)d_in[4];
    const float* b_ih   = (const float*)d_in[5];
    const float* b_hh   = (const float*)d_in[6];
    const float* w_post = (const float*)d_in[7];
    const float* b_post = (const float*)d_in[8];
    const float* w1     = (const float*)d_in[9];
    const float* b1     = (const float*)d_in[10];
    const float* w2     = (const float*)d_in[11];
    const float* b2     = (const float*)d_in[12];
    const float* w3     = (const float*)d_in[13];
    const float* b3     = (const float*)d_in[14];
    float* out = (float*)d_out;

    float* ws     = (float*)d_ws;
    float* s      = ws;                       // 16*8192
    float* gi     = s + NM * TT;              // 8192*384
    float* h_last = gi + (long)TT * G3;       // 128
    float* c_p    = h_last + HH;              // 1
    float* h1     = c_p + 1;                  // 256

    hipLaunchKernelGGL(k_norm, dim3(NM),   dim3(256), 0, stream, samples, s);
    hipLaunchKernelGGL(k_gi,   dim3(TT),   dim3(G3),  0, stream, s, w_ih, b_ih, gi);
    hipLaunchKernelGGL(k_gru,  dim3(1),    dim3(BT),  0, stream, gi, w_hh, b_hh, h_last);
    hipLaunchKernelGGL(k_eig,  dim3(1),    dim3(64),  0, stream, h_last, w_post, b_post, n_src, c_p);
    hipLaunchKernelGGL(k_h1,   dim3(256),  dim3(256), 0, stream, w1, b1, c_p, h1);
    hipLaunchKernelGGL(k_out,  dim3(1),    dim3(256), 0, stream, h1, w2, b2, w3, b3, out);
}

// Round 4
// 3282.327 us; speedup vs baseline: 2.9158x; 1.2692x over previous
//
#include <hip/hip_runtime.h>
#include <math.h>

#define NM 16
#define TT 8192
#define HH 128
#define G3 384
#define BT 256

typedef _Float16 half_t;
typedef _Float16 h2_t __attribute__((ext_vector_type(2)));

#if defined(__has_builtin)
#if __has_builtin(__builtin_amdgcn_fdot2)
#define HAS_FDOT2 1
#endif
#endif

__device__ __forceinline__ float dot2acc(h2_t a, h2_t b, float c) {
#ifdef HAS_FDOT2
    return __builtin_amdgcn_fdot2(a, b, c, false);
#else
    return fmaf((float)a[0], (float)b[0], fmaf((float)a[1], (float)b[1], c));
#endif
}

__device__ __forceinline__ h2_t u2h(unsigned int u) {
    return __builtin_bit_cast(h2_t, u);
}

// pair-sum across lanes (2j, 2j+1) via DPP quad_perm [1,0,3,2] — pure VALU
__device__ __forceinline__ float pair_sum(float x) {
    int y = __builtin_amdgcn_mov_dpp(__builtin_bit_cast(int, x), 0xB1, 0xF, 0xF, true);
    return x + __builtin_bit_cast(float, y);
}

__device__ __forceinline__ float fast_rcp(float x) {
    return __builtin_amdgcn_rcpf(x);
}

// ---------------- K0: per-mic standardize (mean, std ddof=1) ----------------
__global__ void k_norm(const float* __restrict__ samples, float* __restrict__ s_out) {
    int mic = blockIdx.x;
    const float* x = samples + (long)mic * TT;
    __shared__ float red[256];
    int tid = threadIdx.x;
    float acc = 0.f;
    for (int i = tid; i < TT; i += 256) acc += x[i];
    red[tid] = acc; __syncthreads();
    for (int off = 128; off > 0; off >>= 1) { if (tid < off) red[tid] += red[tid + off]; __syncthreads(); }
    float mu = red[0] / (float)TT;
    __syncthreads();
    float acc2 = 0.f;
    for (int i = tid; i < TT; i += 256) { float d = x[i] - mu; acc2 += d * d; }
    red[tid] = acc2; __syncthreads();
    for (int off = 128; off > 0; off >>= 1) { if (tid < off) red[tid] += red[tid + off]; __syncthreads(); }
    float inv = rsqrtf(red[0] / (float)(TT - 1));
    for (int i = tid; i < TT; i += 256) s_out[(long)mic * TT + i] = (x[i] - mu) * inv;
}

// ---------------- K1: gi[t][j] = s[:,t]@w_ih[j] + b_ih[j] (+ b_hh[j] for r/z rows) ----------------
__global__ void k_gi(const float* __restrict__ s, const float* __restrict__ w_ih,
                     const float* __restrict__ b_ih, const float* __restrict__ b_hh,
                     float* __restrict__ gi) {
    int t = blockIdx.x;
    __shared__ float sv[NM];
    int tid = threadIdx.x;            // 0..383
    if (tid < NM) sv[tid] = s[(long)tid * TT + t];
    __syncthreads();
    float acc = b_ih[tid];
    if (tid < 2 * HH) acc += b_hh[tid];   // fold b_hh into r/z gates (n gate: scaled by r, can't fold)
    const float* wr = w_ih + tid * NM;
#pragma unroll
    for (int m = 0; m < NM; ++m) acc += wr[m] * sv[m];
    gi[(long)t * G3 + tid] = acc;
}

// ---------------- K2: sequential GRU scan ----------------
// 256 threads = 4 waves (1/SIMD). Thread t: h-index j=t>>1, k-half=t&1.
// 3 gate half-rows as packed f16 (96 VGPRs). DPP pair-reduce; pointwise
// in-lane with v_rcp (no IEEE divides); ONE barrier/step (dbuf h).
__launch_bounds__(BT, 1)
__global__ void k_gru(const float* __restrict__ gi, const float* __restrict__ w_hh,
                      const float* __restrict__ b_hh, float* __restrict__ h_out) {
    __shared__ __align__(16) half_t hb[2][HH];
    int tid = threadIdx.x;            // 0..255
    int j = tid >> 1;                 // 0..127
    int half = tid & 1;               // k-half
    int k0 = half * 64;

    h2_t wr[32], wz[32], wn[32];
    {
        const float2* r2 = (const float2*)(w_hh + (long)j * HH + k0);
        const float2* z2 = (const float2*)(w_hh + (long)(HH + j) * HH + k0);
        const float2* n2 = (const float2*)(w_hh + (long)(2 * HH + j) * HH + k0);
#pragma unroll
        for (int k = 0; k < 32; ++k) {
            float2 a = r2[k]; wr[k] = h2_t{(half_t)a.x, (half_t)a.y};
            float2 b = z2[k]; wz[k] = h2_t{(half_t)b.x, (half_t)b.y};
            float2 c = n2[k]; wn[k] = h2_t{(half_t)c.x, (half_t)c.y};
        }
    }
    float bhn = b_hh[2 * HH + j];

    if (tid < HH) hb[0][tid] = (half_t)0.f;
    float h_reg = 0.f;
    float gA = gi[j], gB = gi[HH + j], gC = gi[2 * HH + j];
    __syncthreads();

    int p = 0;
    for (int t = 0; t < TT; ++t) {
        // prefetch next step's gi (row TT exists but is dead garbage — never consumed)
        const float* gn = gi + (long)(t + 1) * G3;
        float nA = gn[j], nB = gn[HH + j], nC = gn[2 * HH + j];

        // h half-slice: 8x ds_read_b128, dwords bit-cast to h2 (no pack VALU)
        const uint4* hp = (const uint4*)(&hb[p][k0]);
        float ar0 = 0.f, ar1 = 0.f, az0 = 0.f, az1 = 0.f, an0 = 0.f, an1 = 0.f;
#pragma unroll
        for (int c = 0; c < 8; ++c) {
            uint4 hv = hp[c];
            h2_t p0 = u2h(hv.x), p1 = u2h(hv.y), p2 = u2h(hv.z), p3 = u2h(hv.w);
            int k = c * 4;
            ar0 = dot2acc(wr[k], p0, ar0); ar1 = dot2acc(wr[k + 1], p1, ar1);
            ar0 = dot2acc(wr[k + 2], p2, ar0); ar1 = dot2acc(wr[k + 3], p3, ar1);
            az0 = dot2acc(wz[k], p0, az0); az1 = dot2acc(wz[k + 1], p1, az1);
            az0 = dot2acc(wz[k + 2], p2, az0); az1 = dot2acc(wz[k + 3], p3, az1);
            an0 = dot2acc(wn[k], p0, an0); an1 = dot2acc(wn[k + 1], p1, an1);
            an0 = dot2acc(wn[k + 2], p2, an0); an1 = dot2acc(wn[k + 3], p3, an1);
        }
        // pair-reduce across k-halves (lane^1) via DPP
        float ar = pair_sum(ar0 + ar1);
        float az = pair_sum(az0 + az1);
        float an = pair_sum(an0 + an1);

        // pointwise, in-lane, v_rcp instead of IEEE divide; no clamp needed:
        // e2->inf => rcp->0 => n->1; e2->0 => n->-1 (graceful saturation)
        float xr = gA + ar;                      // b_hh_r pre-folded into gi
        float xz = gB + az;
        float r = fast_rcp(1.f + __expf(-xr));
        float z = fast_rcp(1.f + __expf(-xz));
        float xn = gC + r * (an + bhn);
        float e2 = __expf(2.f * xn);
        float n = 1.f - 2.f * fast_rcp(e2 + 1.f);
        h_reg = n + z * (h_reg - n);
        if (!half) hb[1 - p][j] = (half_t)h_reg;

        gA = nA; gB = nB; gC = nC;
        __syncthreads();
        p ^= 1;
    }
    if (!half) h_out[j] = h_reg;
}

// ---------------- K3: v = w_post@h + b_post; c from rank-1 eigh model ----------------
__global__ void k_eig(const float* __restrict__ h_last, const float* __restrict__ w_post,
                      const float* __restrict__ b_post, const int* __restrict__ ns_p,
                      float* __restrict__ c_out) {
    __shared__ float v[NM];
    int tid = threadIdx.x;
    if (tid < NM) {
        float acc = b_post[tid];
        const float* wr = w_post + tid * HH;
        for (int k = 0; k < HH; ++k) acc += wr[k] * h_last[k];
        v[tid] = acc;
    }
    __syncthreads();
    if (tid == 0) {
        float S1 = 0.f, vv = 0.f;
        for (int i = 0; i < NM; ++i) { S1 += v[i]; vv += v[i] * v[i]; }
        // ||p||^2 = ||P_null 1||^2 ; null dim = NM-1 (rank-1 cov)
        float pp = (float)NM - S1 * S1 / vv;
        int nn = NM - ns_p[0];                      // 13 noise dirs kept of 15
        // chaos-expectation model of LAPACK's degenerate-basis choice:
        float kept = pp * ((float)nn / (float)(NM - 1));
        c_out[0] = 1.f / sqrtf(kept);               // spectrum value (constant over thetas)
    }
}

// ---------------- K4: h1 = gelu(c * rowsum(w1) + b1) ----------------
__global__ void k_h1(const float* __restrict__ w1, const float* __restrict__ b1,
                     const float* __restrict__ c_p, float* __restrict__ h1) {
    int row = blockIdx.x;            // 0..255
    int tid = threadIdx.x;           // 0..255
    const float4* wr = (const float4*)(w1 + (long)row * 65536);
    float acc = 0.f;
    for (int i = tid; i < 16384; i += 256) { float4 x = wr[i]; acc += (x.x + x.y) + (x.z + x.w); }
    __shared__ float red[256];
    red[tid] = acc; __syncthreads();
    for (int off = 128; off > 0; off >>= 1) { if (tid < off) red[tid] += red[tid + off]; __syncthreads(); }
    if (tid == 0) {
        float x = c_p[0] * red[0] + b1[row];
        h1[row] = 0.5f * x * (1.f + erff(x * 0.70710678118654752f));
    }
}

// ---------------- K5: h2 = gelu(w2@h1+b2); out = sigmoid(w3@h2+b3)*2pi ----------------
__global__ void k_out(const float* __restrict__ h1, const float* __restrict__ w2,
                      const float* __restrict__ b2, const float* __restrict__ w3,
                      const float* __restrict__ b3, float* __restrict__ out) {
    __shared__ float h2[256];
    int tid = threadIdx.x;           // 0..255
    float acc = b2[tid];
    const float* wr = w2 + tid * 256;
    for (int k = 0; k < 256; ++k) acc += wr[k] * h1[k];
    h2[tid] = 0.5f * acc * (1.f + erff(acc * 0.70710678118654752f));
    __syncthreads();
    if (tid < NM) {
        float a = b3[tid];
        const float* wr3 = w3 + tid * 256;
        for (int k = 0; k < 256; ++k) a += wr3[k] * h2[k];
        out[tid] = (1.f / (1.f + expf(-a))) * 6.283185307179586f;
    }
}

extern "C" void kernel_launch(void* const* d_in, const int* in_sizes, int n_in,
                              void* d_out, int out_size, void* d_ws, size_t ws_size,
                              hipStream_t stream) {
    const float* samples = (const float*)d_in[0];
    const int*   n_src   = (const int*)d_in[1];
    // d_in[2] = mic_locations: dead (mf==0 -> atheta==1)
    const float* w_ih   = (const float*)d_in[3];
    const float* w_hh   = (const float*)d_in[4];
    const float* b_ih   = (const float*)d_in[5];
    const float* b_hh   = (const float*)d_in[6];
    const float* w_post = (const float*)d_in[7];
    const float* b_post = (const float*)d_in[8];
    const float* w1     = (const float*)d_in[9];
    const float* b1     = (const float*)d_in[10];
    const float* w2     = (const float*)d_in[11];
    const float* b2     = (const float*)d_in[12];
    const float* w3     = (const float*)d_in[13];
    const float* b3     = (const float*)d_in[14];
    float* out = (float*)d_out;

    float* ws     = (float*)d_ws;
    float* s      = ws;                        // 16*8192
    float* gi     = s + NM * TT;               // (8192+1)*384  (row TT = dead prefetch pad)
    float* h_last = gi + (long)(TT + 1) * G3;  // 128
    float* c_p    = h_last + HH;               // 1
    float* h1     = c_p + 1;                   // 256

    hipLaunchKernelGGL(k_norm, dim3(NM),   dim3(256), 0, stream, samples, s);
    hipLaunchKernelGGL(k_gi,   dim3(TT),   dim3(G3),  0, stream, s, w_ih, b_ih, b_hh, gi);
    hipLaunchKernelGGL(k_gru,  dim3(1),    dim3(BT),  0, stream, gi, w_hh, b_hh, h_last);
    hipLaunchKernelGGL(k_eig,  dim3(1),    dim3(64),  0, stream, h_last, w_post, b_post, n_src, c_p);
    hipLaunchKernelGGL(k_h1,   dim3(256),  dim3(256), 0, stream, w1, b1, c_p, h1);
    hipLaunchKernelGGL(k_out,  dim3(1),    dim3(256), 0, stream, h1, w2, b2, w3, b3, out);
}